// Round 14
// baseline (333.239 us; speedup 1.0000x reference)
//
#include <hip/hip_runtime.h>
#include <hip/hip_bf16.h>
#include <cstdint>

typedef __bf16 bf16;
typedef __attribute__((ext_vector_type(8))) __bf16 bf16x8;
typedef __attribute__((ext_vector_type(4))) float f32x4;

#define MFMA16(a, b, c) __builtin_amdgcn_mfma_f32_16x16x32_bf16(a, b, c, 0, 0, 0)

__device__ __forceinline__ float fast_rcp(float x) { return __builtin_amdgcn_rcpf(x); }
__device__ __forceinline__ float silu_f(float x) { return x * fast_rcp(1.f + __expf(-x)); }
__device__ __forceinline__ bf16x8 cvt8(float4 a, float4 b) {
  bf16x8 o;
  o[0]=(bf16)a.x; o[1]=(bf16)a.y; o[2]=(bf16)a.z; o[3]=(bf16)a.w;
  o[4]=(bf16)b.x; o[5]=(bf16)b.y; o[6]=(bf16)b.z; o[7]=(bf16)b.w;
  return o;
}

// ---------------- ws layout (round-5 proven) ----------------
constexpr long WB_IPW1 = 0;
constexpr long WB_IPW2 = 49152;
constexpr long WB_QKV  = 114688;
constexpr long WB_WO   = 704512;
constexpr long WB_W1   = 901120;
constexpr long WB_W2   = 1687552;
constexpr long WB_CPW1 = 2670592;
constexpr long F_ZIN = 5472256;
constexpr long F_G   = F_ZIN + 512L*192*4;
constexpr long F_H   = F_G + 1024;
constexpr long F_QKV = F_H + 512L*256*4;
constexpr long F_S   = F_QKV + 512L*768*4;
constexpr long F_VT  = F_S + 4L*512*512*4;
constexpr long F_O   = F_VT + 4L*64*512*2;
constexpr long F_T1  = F_O + 512L*256*4;
constexpr long O_W2P  = F_T1 + 512L*256*4;
constexpr long O_WDP  = O_W2P + 131072;
constexpr long O_B512 = O_WDP + 262144;

// ---------------- prep — round-5 verbatim ----------------
__global__ __launch_bounds__(256) void prep_kernel(
    const float* __restrict__ s_ipw1, const float* __restrict__ s_ipw2,
    const float* __restrict__ s_qkv,  const float* __restrict__ s_wo,
    const float* __restrict__ s_w1,   const float* __restrict__ s_w2,
    const float* __restrict__ s_dpw1, const float* __restrict__ s_dpw2,
    const float* __restrict__ s_cpw1, bf16* __restrict__ dst,
    const float* __restrict__ z, const int* __restrict__ at, const float* __restrict__ emb,
    const float* __restrict__ zg, const float* __restrict__ gw1, const float* __restrict__ gb1,
    const float* __restrict__ gw2, const float* __restrict__ gb2,
    const float* __restrict__ dpb1,
    float* __restrict__ zi, bf16* __restrict__ w2p, bf16* __restrict__ wdp,
    float* __restrict__ g, float* __restrict__ bias512)
{
  __shared__ float zs[128];
  __shared__ float ts[256];
  const int b = blockIdx.x, tid = threadIdx.x;
  if (b < 2672) {
    long v = (long)b * 256 + tid;
    if (v >= 684032) return;
    const float* src; long off;
    if (v < 176128) {
      if (v < 12288)      { src = s_ipw1; off = 0; }
      else if (v < 28672) { src = s_ipw2; off = 12288; }
      else                { src = s_qkv;  off = 28672; }
    } else if (v < 618496) {
      if (v < 225280)      { src = s_wo; off = 176128; }
      else if (v < 421888) { src = s_w1; off = 225280; }
      else                 { src = s_w2; off = 421888; }
    } else {
      if (v < 651264)      { src = s_dpw1; off = 618496; }
      else if (v < 667648) { src = s_dpw2; off = 651264; }
      else                 { src = s_cpw1; off = 667648; }
    }
    long e = (v - off) * 4;
    float4 f = *(const float4*)&src[e];
    bf16* d = dst + off * 4 + e;
    d[0] = (bf16)f.x; d[1] = (bf16)f.y; d[2] = (bf16)f.z; d[3] = (bf16)f.w;
  } else if (b < 3056) {
    int idx = (b - 2672) * 256 + tid;
    int n = idx / 192, c = idx - n * 192;
    zi[idx] = (c < 128) ? z[n * 128 + c] : emb[at[n] * 64 + (c - 128)];
  } else if (b < 3088) {
    int f = (b - 3056) * 256 + tid;
    int l15 = f & 15, kq = (f >> 4) & 3, ks = (f >> 6) & 7, nt = f >> 9;
    int n = nt * 16 + l15, k0 = ks * 32 + kq * 8;
    float4 v0 = *(const float4*)&s_dpw2[n * 256 + k0];
    float4 v1 = *(const float4*)&s_dpw2[n * 256 + k0 + 4];
    *(bf16x8*)&w2p[(long)f * 8] = cvt8(v0, v1);
  } else if (b < 3216) {
    int v = (b - 3088) * 256 + tid;
    int r = v >> 6, c4 = (v & 63) << 2;
    long src = (r < 256) ? ((long)r * 512 + c4) : ((long)(r - 256) * 512 + 256 + c4);
    float4 f = *(const float4*)&s_dpw1[src];
    bf16* d = &wdp[r * 256 + c4];
    d[0]=(bf16)f.x; d[1]=(bf16)f.y; d[2]=(bf16)f.z; d[3]=(bf16)f.w;
  } else if (b == 3216) {
    if (tid < 128) zs[tid] = zg[tid];
    __syncthreads();
    float s = gb1[tid];
    for (int k = 0; k < 128; ++k) s += zs[k] * gw1[tid * 128 + k];
    ts[tid] = silu_f(s);
    __syncthreads();
    float s2 = gb2[tid];
    for (int k = 0; k < 256; ++k) s2 += ts[k] * gw2[tid * 256 + k];
    g[tid] = s2;
  } else {
    bias512[tid] = dpb1[tid];
    bias512[256 + tid] = 0.f;
  }
}

// ---------------- generic MFMA GEMM, register double-buffered — round-13 validated ----------------
template<int ACT, typename WT>
__global__ __launch_bounds__(256) void gemm_kernel(
    const float* __restrict__ A, int lda, long sA,
    const WT* __restrict__ W, int ldw, long sW,
    const float* __restrict__ bias,
    const float* __restrict__ R, int ldr, long sR,
    float* __restrict__ C, int ldc, long sC, int K)
{
  const int bz = blockIdx.z;
  A += (long)bz * sA;  W += (long)bz * sW;  C += (long)bz * sC;
  if (R) R += (long)bz * sR;
  const int m0 = blockIdx.x * 64, n0 = blockIdx.y * 64;
  __shared__ bf16 As[64][72];
  __shared__ bf16 Ws[64][72];
  const int tid = threadIdx.x;
  const int lane = tid & 63, wid = tid >> 6;
  const int wm = (wid & 1) * 32, wn = (wid >> 1) * 32;
  const int rr = lane & 15, kg = (lane >> 4) << 3;
  f32x4 acc[2][2] = {};

  float4 rA[4];
  float4 rWf[4];
  uint2  rWh[4];

  auto load_tile = [&](int k0) {
#pragma unroll
    for (int r = 0; r < 4; ++r) {
      int lin = tid + r * 256;
      int row = lin >> 4, kc = (lin & 15) << 2;
      rA[r] = *(const float4*)&A[(long)(m0 + row) * lda + k0 + kc];
      if constexpr (sizeof(WT) == 4)
        rWf[r] = *(const float4*)&W[(long)(n0 + row) * ldw + k0 + kc];
      else
        rWh[r] = *(const uint2*)&W[(long)(n0 + row) * ldw + k0 + kc];
    }
  };
  auto store_tile = [&]() {
#pragma unroll
    for (int r = 0; r < 4; ++r) {
      int lin = tid + r * 256;
      int row = lin >> 4, kc = (lin & 15) << 2;
      As[row][kc] = (bf16)rA[r].x; As[row][kc + 1] = (bf16)rA[r].y;
      As[row][kc + 2] = (bf16)rA[r].z; As[row][kc + 3] = (bf16)rA[r].w;
      if constexpr (sizeof(WT) == 4) {
        Ws[row][kc] = (bf16)rWf[r].x; Ws[row][kc + 1] = (bf16)rWf[r].y;
        Ws[row][kc + 2] = (bf16)rWf[r].z; Ws[row][kc + 3] = (bf16)rWf[r].w;
      } else {
        *(uint2*)&Ws[row][kc] = rWh[r];
      }
    }
  };
  auto do_mfma = [&]() {
#pragma unroll
    for (int ks = 0; ks < 2; ++ks) {
      const int kk = ks * 32 + kg;
      bf16x8 a0 = *(const bf16x8*)&As[wm + rr][kk];
      bf16x8 a1 = *(const bf16x8*)&As[wm + 16 + rr][kk];
      bf16x8 b0 = *(const bf16x8*)&Ws[wn + rr][kk];
      bf16x8 b1 = *(const bf16x8*)&Ws[wn + 16 + rr][kk];
      acc[0][0] = MFMA16(a0, b0, acc[0][0]);
      acc[0][1] = MFMA16(a0, b1, acc[0][1]);
      acc[1][0] = MFMA16(a1, b0, acc[1][0]);
      acc[1][1] = MFMA16(a1, b1, acc[1][1]);
    }
  };

  load_tile(0);
  store_tile();
  __syncthreads();
  for (int k0 = 64; k0 < K; k0 += 64) {
    load_tile(k0);
    do_mfma();
    __syncthreads();
    store_tile();
    __syncthreads();
  }
  do_mfma();

  const int rg = lane >> 4;
#pragma unroll
  for (int mi = 0; mi < 2; ++mi)
#pragma unroll
    for (int ni = 0; ni < 2; ++ni)
#pragma unroll
      for (int r = 0; r < 4; ++r) {
        int gm = m0 + wm + mi * 16 + rg * 4 + r;
        int gn = n0 + wn + ni * 16 + rr;
        float v = acc[mi][ni][r];
        if (bias) v += bias[gn];
        if (R) v += R[(long)gm * ldr + gn];
        if (ACT == 1) v = silu_f(v);
        else if (ACT == 2) v = fmaxf(v, 0.f);
        C[(long)gm * ldc + gn] = v;
      }
}

// ---------------- merged QK^T (b<256) + V-transpose (b>=256) ----------------
// qk blocks: head = b>>6, m0 = (b&7)*64, n0 = ((b>>3)&7)*64; single K=64 tile.
__global__ __launch_bounds__(256) void qkvt_kernel(
    const float* __restrict__ qkv, float* __restrict__ S, bf16* __restrict__ vt)
{
  __shared__ bf16 As[64][72];
  __shared__ bf16 Ws[64][72];
  const int b = blockIdx.x, tid = threadIdx.x;
  if (b >= 256) {                     // V transpose (round-5 verbatim body)
    int idx = (b - 256) * 256 + tid;
    int hh = idx >> 15;
    int r = idx & 32767;
    int d = r >> 9, n = r & 511;
    vt[idx] = (bf16)qkv[(long)n * 768 + 512 + hh * 64 + d];
    return;
  }
  const int h = b >> 6, m0 = (b & 7) * 64, n0 = ((b >> 3) & 7) * 64;
  const float* A = qkv + h * 64;          // q slice, ld 768
  const float* W = qkv + 256 + h * 64;    // k slice, ld 768
  float* C = S + (long)h * 262144;
  const int lane = tid & 63, wid = tid >> 6;
  const int wm = (wid & 1) * 32, wn = (wid >> 1) * 32;
  const int rr = lane & 15, kg = (lane >> 4) << 3;
#pragma unroll
  for (int r = 0; r < 4; ++r) {
    int lin = tid + r * 256;
    int row = lin >> 4, kc = (lin & 15) << 2;
    float4 va = *(const float4*)&A[(long)(m0 + row) * 768 + kc];
    As[row][kc] = (bf16)va.x; As[row][kc + 1] = (bf16)va.y;
    As[row][kc + 2] = (bf16)va.z; As[row][kc + 3] = (bf16)va.w;
    float4 vw = *(const float4*)&W[(long)(n0 + row) * 768 + kc];
    Ws[row][kc] = (bf16)vw.x; Ws[row][kc + 1] = (bf16)vw.y;
    Ws[row][kc + 2] = (bf16)vw.z; Ws[row][kc + 3] = (bf16)vw.w;
  }
  __syncthreads();
  f32x4 acc[2][2] = {};
#pragma unroll
  for (int ks = 0; ks < 2; ++ks) {
    const int kk = ks * 32 + kg;
    bf16x8 a0 = *(const bf16x8*)&As[wm + rr][kk];
    bf16x8 a1 = *(const bf16x8*)&As[wm + 16 + rr][kk];
    bf16x8 b0 = *(const bf16x8*)&Ws[wn + rr][kk];
    bf16x8 b1 = *(const bf16x8*)&Ws[wn + 16 + rr][kk];
    acc[0][0] = MFMA16(a0, b0, acc[0][0]);
    acc[0][1] = MFMA16(a0, b1, acc[0][1]);
    acc[1][0] = MFMA16(a1, b0, acc[1][0]);
    acc[1][1] = MFMA16(a1, b1, acc[1][1]);
  }
  const int rg = lane >> 4;
#pragma unroll
  for (int mi = 0; mi < 2; ++mi)
#pragma unroll
    for (int ni = 0; ni < 2; ++ni)
#pragma unroll
      for (int r = 0; r < 4; ++r) {
        int gm = m0 + wm + mi * 16 + rg * 4 + r;
        int gn = n0 + wn + ni * 16 + rr;
        C[(long)gm * 512 + gn] = acc[mi][ni][r];
      }
}

// ---------------- fused softmax + PV — round-8 validated body ----------------
__global__ __launch_bounds__(256) void softmax_pv_kernel(
    const float* __restrict__ S, const bf16* __restrict__ Vt, float* __restrict__ o)
{
  const int row = blockIdx.x, h = blockIdx.y;
  const float* srow = S + ((long)h * 512 + row) * 512;
  __shared__ float p_s[512];
  __shared__ float red[4];
  __shared__ float red2[4];
  __shared__ float part[64][4];
  const int tid = threadIdx.x;
  float a = srow[tid] * 0.125f, b = srow[tid + 256] * 0.125f;
  float m = fmaxf(a, b);
#pragma unroll
  for (int t = 1; t < 64; t <<= 1) m = fmaxf(m, __shfl_xor(m, t));
  int wid = tid >> 6;
  if ((tid & 63) == 0) red[wid] = m;
  __syncthreads();
  m = fmaxf(fmaxf(red[0], red[1]), fmaxf(red[2], red[3]));
  float e0 = __expf(a - m), e1 = __expf(b - m);
  float s = e0 + e1;
#pragma unroll
  for (int t = 1; t < 64; t <<= 1) s += __shfl_xor(s, t);
  if ((tid & 63) == 0) red2[wid] = s;
  __syncthreads();
  s = red2[0] + red2[1] + red2[2] + red2[3];
  float inv = fast_rcp(s);
  p_s[tid] = e0 * inv; p_s[tid + 256] = e1 * inv;
  __syncthreads();
  const int d = tid & 63, kc = tid >> 6;
  const bf16* vp = Vt + (long)h * 32768 + (long)d * 512 + kc * 128;
  const float* pp = &p_s[kc * 128];
  float acc = 0.f;
#pragma unroll
  for (int k = 0; k < 128; k += 8) {
    bf16x8 vv = *(const bf16x8*)&vp[k];
    acc += pp[k]     * (float)vv[0] + pp[k + 1] * (float)vv[1]
         + pp[k + 2] * (float)vv[2] + pp[k + 3] * (float)vv[3]
         + pp[k + 4] * (float)vv[4] + pp[k + 5] * (float)vv[5]
         + pp[k + 6] * (float)vv[6] + pp[k + 7] * (float)vv[7];
  }
  part[d][kc] = acc;
  __syncthreads();
  if (tid < 64)
    o[(long)row * 256 + h * 64 + tid] = part[tid][0] + part[tid][1] + part[tid][2] + part[tid][3];
}

// ---------------- LayerNorm — round-5 verbatim ----------------
__global__ __launch_bounds__(256) void ln_kernel(
    const float* __restrict__ X, const float* __restrict__ sc,
    const float* __restrict__ bi, float* __restrict__ Y)
{
  int row = blockIdx.x, tid = threadIdx.x;
  float v = X[(long)row * 256 + tid];
  float s = v;
#pragma unroll
  for (int o = 1; o < 64; o <<= 1) s += __shfl_xor(s, o);
  __shared__ float r1[4];
  __shared__ float r2[4];
  if ((tid & 63) == 0) r1[tid >> 6] = s;
  __syncthreads();
  float mean = (r1[0] + r1[1] + r1[2] + r1[3]) * (1.f / 256.f);
  float d = v - mean;
  float t = d * d;
#pragma unroll
  for (int o = 1; o < 64; o <<= 1) t += __shfl_xor(t, o);
  if ((tid & 63) == 0) r2[tid >> 6] = t;
  __syncthreads();
  float var = (r2[0] + r2[1] + r2[2] + r2[3]) * (1.f / 256.f);
  Y[(long)row * 256 + tid] = d * rsqrtf(var + 1e-5f) * sc[tid] + bi[tid];
}

// ---------------- tail: aiaj (y<8) + coord-hidden (y>=8), both read h, K=256 ----------------
__global__ __launch_bounds__(256) void tail_kernel(
    const float* __restrict__ hsrc,
    const bf16* __restrict__ WDP, const float* __restrict__ b512, float* __restrict__ aiaj,
    const bf16* __restrict__ Wcp, const float* __restrict__ cpb1, float* __restrict__ ct)
{
  const int y = blockIdx.y;
  const bf16* W; const float* bias; float* C; int ldc, n0; bool act;
  if (y < 8) { W = WDP; bias = b512; C = aiaj; ldc = 512; n0 = y * 64; act = false; }
  else       { W = Wcp; bias = cpb1; C = ct;   ldc = 256; n0 = (y - 8) * 64; act = true; }
  const int m0 = blockIdx.x * 64;
  __shared__ bf16 As[64][72];
  __shared__ bf16 Ws[64][72];
  const int tid = threadIdx.x;
  const int lane = tid & 63, wid = tid >> 6;
  const int wm = (wid & 1) * 32, wn = (wid >> 1) * 32;
  const int rr = lane & 15, kg = (lane >> 4) << 3;
  f32x4 acc[2][2] = {};
  float4 rA[4];
  uint2  rWh[4];
  auto load_tile = [&](int k0) {
#pragma unroll
    for (int r = 0; r < 4; ++r) {
      int lin = tid + r * 256;
      int row = lin >> 4, kc = (lin & 15) << 2;
      rA[r] = *(const float4*)&hsrc[(long)(m0 + row) * 256 + k0 + kc];
      rWh[r] = *(const uint2*)&W[(long)(n0 + row) * 256 + k0 + kc];
    }
  };
  auto store_tile = [&]() {
#pragma unroll
    for (int r = 0; r < 4; ++r) {
      int lin = tid + r * 256;
      int row = lin >> 4, kc = (lin & 15) << 2;
      As[row][kc] = (bf16)rA[r].x; As[row][kc + 1] = (bf16)rA[r].y;
      As[row][kc + 2] = (bf16)rA[r].z; As[row][kc + 3] = (bf16)rA[r].w;
      *(uint2*)&Ws[row][kc] = rWh[r];
    }
  };
  auto do_mfma = [&]() {
#pragma unroll
    for (int ks = 0; ks < 2; ++ks) {
      const int kk = ks * 32 + kg;
      bf16x8 a0 = *(const bf16x8*)&As[wm + rr][kk];
      bf16x8 a1 = *(const bf16x8*)&As[wm + 16 + rr][kk];
      bf16x8 b0 = *(const bf16x8*)&Ws[wn + rr][kk];
      bf16x8 b1 = *(const bf16x8*)&Ws[wn + 16 + rr][kk];
      acc[0][0] = MFMA16(a0, b0, acc[0][0]);
      acc[0][1] = MFMA16(a0, b1, acc[0][1]);
      acc[1][0] = MFMA16(a1, b0, acc[1][0]);
      acc[1][1] = MFMA16(a1, b1, acc[1][1]);
    }
  };
  load_tile(0);
  store_tile();
  __syncthreads();
  for (int k0 = 64; k0 < 256; k0 += 64) {
    load_tile(k0);
    do_mfma();
    __syncthreads();
    store_tile();
    __syncthreads();
  }
  do_mfma();
  const int rg = lane >> 4;
#pragma unroll
  for (int mi = 0; mi < 2; ++mi)
#pragma unroll
    for (int ni = 0; ni < 2; ++ni)
#pragma unroll
      for (int r = 0; r < 4; ++r) {
        int gm = m0 + wm + mi * 16 + rg * 4 + r;
        int gn = n0 + wn + ni * 16 + rr;
        float v = acc[mi][ni][r] + bias[gn];
        if (act) v = silu_f(v);
        C[(long)gm * ldc + gn] = v;
      }
}

// ---------------- pair2 v4 — round-10 validated (87 µs) ----------------
#define P2_BUILD(CIDX, TBUF)                                                     \
  {                                                                              \
    const int j0b = jbase + (CIDX) * 32;                                         \
    const float* ajp = aj + (long)(j0b + pp) * 512;                              \
    _Pragma("unroll")                                                            \
    for (int r = 0; r < 4; ++r) {                                                \
      int kk = kb + 8 * r;                                                       \
      float4 a0 = *(const float4*)(ajp + kk * 8);                                \
      float4 a1 = *(const float4*)(ajp + kk * 8 + 4);                            \
      const float* aip = ai_s + kk * 8;                                          \
      bf16x8 tv;                                                                 \
      tv[0] = (bf16)silu_f(a0.x + aip[0]); tv[1] = (bf16)silu_f(a0.y + aip[1]);  \
      tv[2] = (bf16)silu_f(a0.z + aip[2]); tv[3] = (bf16)silu_f(a0.w + aip[3]);  \
      tv[4] = (bf16)silu_f(a1.x + aip[4]); tv[5] = (bf16)silu_f(a1.y + aip[5]);  \
      tv[6] = (bf16)silu_f(a1.z + aip[6]); tv[7] = (bf16)silu_f(a1.w + aip[7]);  \
      *(bf16x8*)&TBUF[(kk * 32 + pp) * 8] = tv;                                  \
    }                                                                            \
  }

#define P2_MFMA(TBUF, ACC)                                                       \
  _Pragma("unroll")                                                              \
  for (int ks = 0; ks < 8; ++ks) {                                               \
    bf16x8 af0 = *(const bf16x8*)&TBUF[((ks * 4 + kq) * 32 + l15) * 8];          \
    bf16x8 af1 = *(const bf16x8*)&TBUF[((ks * 4 + kq) * 32 + 16 + l15) * 8];     \
    _Pragma("unroll")                                                            \
    for (int nt = 0; nt < 4; ++nt) {                                             \
      bf16x8 bfv = *(const bf16x8*)(w2base + (long)(nt * 8 + ks) * 512);         \
      ACC[0][nt] = MFMA16(af0, bfv, ACC[0][nt]);                                 \
      ACC[1][nt] = MFMA16(af1, bfv, ACC[1][nt]);                                 \
    }                                                                            \
  }

#define P2_EPI(ACC, PBUF)                                                        \
  _Pragma("unroll")                                                              \
  for (int Mt = 0; Mt < 2; ++Mt)                                                 \
    _Pragma("unroll")                                                            \
    for (int r = 0; r < 4; ++r) {                                                \
      float s = silu_f(ACC[Mt][0][r] + b2v[0]) * w3v[0]                          \
              + silu_f(ACC[Mt][1][r] + b2v[1]) * w3v[1]                          \
              + silu_f(ACC[Mt][2][r] + b2v[2]) * w3v[2]                          \
              + silu_f(ACC[Mt][3][r] + b2v[3]) * w3v[3];                         \
      s += __shfl_xor(s, 1); s += __shfl_xor(s, 2);                              \
      s += __shfl_xor(s, 4); s += __shfl_xor(s, 8);                              \
      if (l15 == 0) PBUF[Mt * 16 + kq * 4 + r][w] = s;                           \
    }

#define P2_DIST(CIDX, PBUF)                                                      \
  if (tid < 32) {                                                                \
    float s = PBUF[tid][0] + PBUF[tid][1] + PBUF[tid][2] + PBUF[tid][3] + b3v;   \
    float dd = fmaxf(s, 0.f) + log1pf(__expf(-fabsf(s)));                        \
    dout[(long)i * 512 + jbase + (CIDX) * 32 + tid] = dd;                        \
  }

__global__ __launch_bounds__(256, 2) void pair2_kernel(
    const float* __restrict__ ai, const float* __restrict__ aj,
    const bf16* __restrict__ W2P, const float* __restrict__ b2g,
    const float* __restrict__ w3g, const float* __restrict__ b3p,
    float* __restrict__ dout)
{
  __shared__ float ai_s[256];
  __shared__ bf16 t0_s[32 * 256];
  __shared__ bf16 t1_s[32 * 256];
  __shared__ float p0_s[32][4];
  __shared__ float p1_s[32][4];
  const int tid = threadIdx.x, lane = tid & 63, w = tid >> 6;
  const int l15 = lane & 15, kq = lane >> 4;
  const int pp = tid & 31, kb = tid >> 5;
  const int i = blockIdx.x >> 1, half = blockIdx.x & 1;
  const int jbase = half * 256;
  const float b3v = b3p[0];

  ai_s[tid] = ai[(long)i * 512 + tid];

  float b2v[4], w3v[4];
#pragma unroll
  for (int nt = 0; nt < 4; ++nt) {
    int ntg = w * 4 + nt;
    b2v[nt] = b2g[ntg * 16 + l15];
    w3v[nt] = w3g[ntg * 16 + l15];
  }
  const bf16* w2base = W2P + ((long)((w * 128 + kq) * 16 + l15)) * 8;
  __syncthreads();

  P2_BUILD(0, t0_s);
  __syncthreads();
#pragma unroll 1
  for (int cp = 0; cp < 4; ++cp) {
    const int c0 = cp * 2, c1 = cp * 2 + 1;
    {
      f32x4 acc[2][4] = {};
      P2_MFMA(t0_s, acc);
      P2_BUILD(c1, t1_s);
      P2_EPI(acc, p0_s);
    }
    __syncthreads();
    P2_DIST(c0, p0_s);
    {
      f32x4 acc[2][4] = {};
      P2_MFMA(t1_s, acc);
      if (cp < 3) P2_BUILD(c1 + 1, t0_s);
      P2_EPI(acc, p1_s);
    }
    __syncthreads();
    P2_DIST(c1, p1_s);
  }
}

// ---------------- symmetrize (b<1024) + coord final (b>=1024) ----------------
__global__ __launch_bounds__(256) void symcoord_kernel(
    float* __restrict__ dist,
    const float* __restrict__ ct, const float* __restrict__ w2,
    const float* __restrict__ b2, float* __restrict__ out)
{
  const int b = blockIdx.x, tid = threadIdx.x;
  if (b < 1024) {
    int idx = b * 256 + tid;
    int i = idx >> 9, j = idx & 511;
    if (i < j) {
      float a = dist[idx];
      float bb = dist[(long)j * 512 + i];
      float m = 0.5f * (a + bb);
      dist[idx] = m;
      dist[(long)j * 512 + i] = m;
    }
  } else {
    int t = (b - 1024) * 256 + tid;
    if (t >= 1536) return;
    int row = t / 3, c = t - row * 3;
    float s = b2[c];
    const float* a = &ct[(long)row * 256];
    const float* wp = &w2[c * 256];
    for (int k = 0; k < 256; ++k) s += a[k] * wp[k];
    out[t] = s;
  }
}

extern "C" void kernel_launch(void* const* d_in, const int* in_sizes, int n_in,
                              void* d_out, int out_size, void* d_ws, size_t ws_size,
                              hipStream_t stream) {
  const float* z        = (const float*)d_in[0];
  const float* z_global = (const float*)d_in[1];
  const int*   atom_t   = (const int*)d_in[2];
  const float* emb      = (const float*)d_in[3];
  const float* ip_w1 = (const float*)d_in[4];  const float* ip_b1 = (const float*)d_in[5];
  const float* ip_w2 = (const float*)d_in[6];  const float* ip_b2 = (const float*)d_in[7];
  const float* gp_w1 = (const float*)d_in[8];  const float* gp_b1 = (const float*)d_in[9];
  const float* gp_w2 = (const float*)d_in[10]; const float* gp_b2 = (const float*)d_in[11];
  const float* wqkv  = (const float*)d_in[12]; const float* bqkv  = (const float*)d_in[13];
  const float* wo    = (const float*)d_in[14]; const float* bo    = (const float*)d_in[15];
  const float* ln1s  = (const float*)d_in[16]; const float* ln1b  = (const float*)d_in[17];
  const float* w1    = (const float*)d_in[18]; const float* b1    = (const float*)d_in[19];
  const float* w2    = (const float*)d_in[20]; const float* b2    = (const float*)d_in[21];
  const float* ln2s  = (const float*)d_in[22]; const float* ln2b  = (const float*)d_in[23];
  const float* dpw1  = (const float*)d_in[24]; const float* dpb1  = (const float*)d_in[25];
  const float* dpw2  = (const float*)d_in[26]; const float* dpb2  = (const float*)d_in[27];
  const float* dpw3  = (const float*)d_in[28]; const float* dpb3  = (const float*)d_in[29];
  const float* cpw1  = (const float*)d_in[30]; const float* cpb1  = (const float*)d_in[31];
  const float* cpw2  = (const float*)d_in[32]; const float* cpb2  = (const float*)d_in[33];

  char* ws = (char*)d_ws;
  bf16*  WB   = (bf16*)ws;
  float* zin  = (float*)(ws + F_ZIN);
  float* g    = (float*)(ws + F_G);
  float* h    = (float*)(ws + F_H);
  float* qkv  = (float*)(ws + F_QKV);
  float* S    = (float*)(ws + F_S);
  bf16*  Vt   = (bf16*)(ws + F_VT);
  float* o    = (float*)(ws + F_O);
  float* t1   = (float*)(ws + F_T1);
  bf16*  W2P  = (bf16*)(ws + O_W2P);
  bf16*  WDP  = (bf16*)(ws + O_WDP);
  float* b512 = (float*)(ws + O_B512);
  float* ff1  = S;
  float* aiaj = S;
  float* out  = (float*)d_out;
  float* xout = out;
  float* dist = out + 1536;

  prep_kernel<<<3218, 256, 0, stream>>>(ip_w1, ip_w2, wqkv, wo, w1, w2, dpw1, dpw2, cpw1, WB,
      z, atom_t, emb, z_global, gp_w1, gp_b1, gp_w2, gp_b2, dpb1,
      zin, W2P, WDP, g, b512);

  gemm_kernel<1, bf16><<<dim3(8, 4, 1), 256, 0, stream>>>(zin, 192, 0, WB + WB_IPW1, 192, 0,
      ip_b1, nullptr, 0, 0, t1, 256, 0, 192);
  gemm_kernel<0, bf16><<<dim3(8, 4, 1), 256, 0, stream>>>(t1, 256, 0, WB + WB_IPW2, 256, 0,
      ip_b2, g, 0, 0, h, 256, 0, 256);

  for (int l = 0; l < 3; ++l) {
    const bf16* wq = WB + WB_QKV + (long)l * 768 * 256;
    gemm_kernel<0, bf16><<<dim3(8, 12, 1), 256, 0, stream>>>(h, 256, 0, wq, 256, 0,
        bqkv + l * 768, nullptr, 0, 0, qkv, 768, 0, 256);
    qkvt_kernel<<<768, 256, 0, stream>>>(qkv, S, Vt);
    softmax_pv_kernel<<<dim3(512, 4), 256, 0, stream>>>(S, Vt, o);
    gemm_kernel<0, bf16><<<dim3(8, 4, 1), 256, 0, stream>>>(o, 256, 0,
        WB + WB_WO + (long)l * 65536, 256, 0, bo + l * 256, h, 256, 0, t1, 256, 0, 256);
    ln_kernel<<<512, 256, 0, stream>>>(t1, ln1s + l * 256, ln1b + l * 256, h);
    gemm_kernel<2, bf16><<<dim3(8, 16, 1), 256, 0, stream>>>(h, 256, 0,
        WB + WB_W1 + (long)l * 262144, 256, 0, b1 + l * 1024, nullptr, 0, 0, ff1, 1024, 0, 256);
    gemm_kernel<0, bf16><<<dim3(8, 4, 1), 256, 0, stream>>>(ff1, 1024, 0,
        WB + WB_W2 + (long)l * 262144, 1024, 0, b2 + l * 256, h, 256, 0, t1, 256, 0, 1024);
    ln_kernel<<<512, 256, 0, stream>>>(t1, ln2s + l * 256, ln2b + l * 256, h);
  }

  // aiaj (y<8) + coord hidden (y>=8), both from h
  tail_kernel<<<dim3(8, 12), 256, 0, stream>>>(h, WDP, b512, aiaj,
      WB + WB_CPW1, cpb1, t1);
  pair2_kernel<<<1024, 256, 0, stream>>>(aiaj, aiaj + 256, W2P, dpb2, dpw3, dpb3, dist);
  symcoord_kernel<<<1030, 256, 0, stream>>>(dist, t1, cpw2, cpb2, xout);
}

// Round 15
// 317.286 us; speedup vs baseline: 1.0503x; 1.0503x over previous
//
#include <hip/hip_runtime.h>
#include <hip/hip_bf16.h>
#include <cstdint>

typedef __bf16 bf16;
typedef __attribute__((ext_vector_type(8))) __bf16 bf16x8;
typedef __attribute__((ext_vector_type(4))) float f32x4;

#define MFMA16(a, b, c) __builtin_amdgcn_mfma_f32_16x16x32_bf16(a, b, c, 0, 0, 0)

__device__ __forceinline__ float fast_rcp(float x) { return __builtin_amdgcn_rcpf(x); }
__device__ __forceinline__ float silu_f(float x) { return x * fast_rcp(1.f + __expf(-x)); }
__device__ __forceinline__ bf16x8 cvt8(float4 a, float4 b) {
  bf16x8 o;
  o[0]=(bf16)a.x; o[1]=(bf16)a.y; o[2]=(bf16)a.z; o[3]=(bf16)a.w;
  o[4]=(bf16)b.x; o[5]=(bf16)b.y; o[6]=(bf16)b.z; o[7]=(bf16)b.w;
  return o;
}

// ---------------- ws layout (round-5 proven) ----------------
constexpr long WB_IPW1 = 0;
constexpr long WB_IPW2 = 49152;
constexpr long WB_QKV  = 114688;
constexpr long WB_WO   = 704512;
constexpr long WB_W1   = 901120;
constexpr long WB_W2   = 1687552;
constexpr long WB_CPW1 = 2670592;
constexpr long F_ZIN = 5472256;
constexpr long F_G   = F_ZIN + 512L*192*4;
constexpr long F_H   = F_G + 1024;
constexpr long F_QKV = F_H + 512L*256*4;
constexpr long F_S   = F_QKV + 512L*768*4;
constexpr long F_VT  = F_S + 4L*512*512*4;
constexpr long F_O   = F_VT + 4L*64*512*2;
constexpr long F_T1  = F_O + 512L*256*4;
constexpr long O_W2P  = F_T1 + 512L*256*4;
constexpr long O_WDP  = O_W2P + 131072;
constexpr long O_B512 = O_WDP + 262144;

// ---------------- prep — round-5 verbatim ----------------
__global__ __launch_bounds__(256) void prep_kernel(
    const float* __restrict__ s_ipw1, const float* __restrict__ s_ipw2,
    const float* __restrict__ s_qkv,  const float* __restrict__ s_wo,
    const float* __restrict__ s_w1,   const float* __restrict__ s_w2,
    const float* __restrict__ s_dpw1, const float* __restrict__ s_dpw2,
    const float* __restrict__ s_cpw1, bf16* __restrict__ dst,
    const float* __restrict__ z, const int* __restrict__ at, const float* __restrict__ emb,
    const float* __restrict__ zg, const float* __restrict__ gw1, const float* __restrict__ gb1,
    const float* __restrict__ gw2, const float* __restrict__ gb2,
    const float* __restrict__ dpb1,
    float* __restrict__ zi, bf16* __restrict__ w2p, bf16* __restrict__ wdp,
    float* __restrict__ g, float* __restrict__ bias512)
{
  __shared__ float zs[128];
  __shared__ float ts[256];
  const int b = blockIdx.x, tid = threadIdx.x;
  if (b < 2672) {
    long v = (long)b * 256 + tid;
    if (v >= 684032) return;
    const float* src; long off;
    if (v < 176128) {
      if (v < 12288)      { src = s_ipw1; off = 0; }
      else if (v < 28672) { src = s_ipw2; off = 12288; }
      else                { src = s_qkv;  off = 28672; }
    } else if (v < 618496) {
      if (v < 225280)      { src = s_wo; off = 176128; }
      else if (v < 421888) { src = s_w1; off = 225280; }
      else                 { src = s_w2; off = 421888; }
    } else {
      if (v < 651264)      { src = s_dpw1; off = 618496; }
      else if (v < 667648) { src = s_dpw2; off = 651264; }
      else                 { src = s_cpw1; off = 667648; }
    }
    long e = (v - off) * 4;
    float4 f = *(const float4*)&src[e];
    bf16* d = dst + off * 4 + e;
    d[0] = (bf16)f.x; d[1] = (bf16)f.y; d[2] = (bf16)f.z; d[3] = (bf16)f.w;
  } else if (b < 3056) {
    int idx = (b - 2672) * 256 + tid;
    int n = idx / 192, c = idx - n * 192;
    zi[idx] = (c < 128) ? z[n * 128 + c] : emb[at[n] * 64 + (c - 128)];
  } else if (b < 3088) {
    int f = (b - 3056) * 256 + tid;
    int l15 = f & 15, kq = (f >> 4) & 3, ks = (f >> 6) & 7, nt = f >> 9;
    int n = nt * 16 + l15, k0 = ks * 32 + kq * 8;
    float4 v0 = *(const float4*)&s_dpw2[n * 256 + k0];
    float4 v1 = *(const float4*)&s_dpw2[n * 256 + k0 + 4];
    *(bf16x8*)&w2p[(long)f * 8] = cvt8(v0, v1);
  } else if (b < 3216) {
    int v = (b - 3088) * 256 + tid;
    int r = v >> 6, c4 = (v & 63) << 2;
    long src = (r < 256) ? ((long)r * 512 + c4) : ((long)(r - 256) * 512 + 256 + c4);
    float4 f = *(const float4*)&s_dpw1[src];
    bf16* d = &wdp[r * 256 + c4];
    d[0]=(bf16)f.x; d[1]=(bf16)f.y; d[2]=(bf16)f.z; d[3]=(bf16)f.w;
  } else if (b == 3216) {
    if (tid < 128) zs[tid] = zg[tid];
    __syncthreads();
    float s = gb1[tid];
    for (int k = 0; k < 128; ++k) s += zs[k] * gw1[tid * 128 + k];
    ts[tid] = silu_f(s);
    __syncthreads();
    float s2 = gb2[tid];
    for (int k = 0; k < 256; ++k) s2 += ts[k] * gw2[tid * 256 + k];
    g[tid] = s2;
  } else {
    bias512[tid] = dpb1[tid];
    bias512[256 + tid] = 0.f;
  }
}

// ---------------- generic MFMA GEMM, register double-buffered — round-13 validated ----------------
template<int ACT, typename WT>
__global__ __launch_bounds__(256) void gemm_kernel(
    const float* __restrict__ A, int lda, long sA,
    const WT* __restrict__ W, int ldw, long sW,
    const float* __restrict__ bias,
    const float* __restrict__ R, int ldr, long sR,
    float* __restrict__ C, int ldc, long sC, int K)
{
  const int bz = blockIdx.z;
  A += (long)bz * sA;  W += (long)bz * sW;  C += (long)bz * sC;
  if (R) R += (long)bz * sR;
  const int m0 = blockIdx.x * 64, n0 = blockIdx.y * 64;
  __shared__ bf16 As[64][72];
  __shared__ bf16 Ws[64][72];
  const int tid = threadIdx.x;
  const int lane = tid & 63, wid = tid >> 6;
  const int wm = (wid & 1) * 32, wn = (wid >> 1) * 32;
  const int rr = lane & 15, kg = (lane >> 4) << 3;
  f32x4 acc[2][2] = {};

  float4 rA[4];
  float4 rWf[4];
  uint2  rWh[4];

  auto load_tile = [&](int k0) {
#pragma unroll
    for (int r = 0; r < 4; ++r) {
      int lin = tid + r * 256;
      int row = lin >> 4, kc = (lin & 15) << 2;
      rA[r] = *(const float4*)&A[(long)(m0 + row) * lda + k0 + kc];
      if constexpr (sizeof(WT) == 4)
        rWf[r] = *(const float4*)&W[(long)(n0 + row) * ldw + k0 + kc];
      else
        rWh[r] = *(const uint2*)&W[(long)(n0 + row) * ldw + k0 + kc];
    }
  };
  auto store_tile = [&]() {
#pragma unroll
    for (int r = 0; r < 4; ++r) {
      int lin = tid + r * 256;
      int row = lin >> 4, kc = (lin & 15) << 2;
      As[row][kc] = (bf16)rA[r].x; As[row][kc + 1] = (bf16)rA[r].y;
      As[row][kc + 2] = (bf16)rA[r].z; As[row][kc + 3] = (bf16)rA[r].w;
      if constexpr (sizeof(WT) == 4) {
        Ws[row][kc] = (bf16)rWf[r].x; Ws[row][kc + 1] = (bf16)rWf[r].y;
        Ws[row][kc + 2] = (bf16)rWf[r].z; Ws[row][kc + 3] = (bf16)rWf[r].w;
      } else {
        *(uint2*)&Ws[row][kc] = rWh[r];
      }
    }
  };
  auto do_mfma = [&]() {
#pragma unroll
    for (int ks = 0; ks < 2; ++ks) {
      const int kk = ks * 32 + kg;
      bf16x8 a0 = *(const bf16x8*)&As[wm + rr][kk];
      bf16x8 a1 = *(const bf16x8*)&As[wm + 16 + rr][kk];
      bf16x8 b0 = *(const bf16x8*)&Ws[wn + rr][kk];
      bf16x8 b1 = *(const bf16x8*)&Ws[wn + 16 + rr][kk];
      acc[0][0] = MFMA16(a0, b0, acc[0][0]);
      acc[0][1] = MFMA16(a0, b1, acc[0][1]);
      acc[1][0] = MFMA16(a1, b0, acc[1][0]);
      acc[1][1] = MFMA16(a1, b1, acc[1][1]);
    }
  };

  load_tile(0);
  store_tile();
  __syncthreads();
  for (int k0 = 64; k0 < K; k0 += 64) {
    load_tile(k0);
    do_mfma();
    __syncthreads();
    store_tile();
    __syncthreads();
  }
  do_mfma();

  const int rg = lane >> 4;
#pragma unroll
  for (int mi = 0; mi < 2; ++mi)
#pragma unroll
    for (int ni = 0; ni < 2; ++ni)
#pragma unroll
      for (int r = 0; r < 4; ++r) {
        int gm = m0 + wm + mi * 16 + rg * 4 + r;
        int gn = n0 + wn + ni * 16 + rr;
        float v = acc[mi][ni][r];
        if (bias) v += bias[gn];
        if (R) v += R[(long)gm * ldr + gn];
        if (ACT == 1) v = silu_f(v);
        else if (ACT == 2) v = fmaxf(v, 0.f);
        C[(long)gm * ldc + gn] = v;
      }
}

// ---------------- merged softmax (b<2048) + V-transpose (b>=2048) — round-10 validated ----------------
__global__ __launch_bounds__(256) void softvt_kernel(
    float* __restrict__ S, const float* __restrict__ qkv, bf16* __restrict__ vt)
{
  const int b = blockIdx.x, tid = threadIdx.x;
  if (b < 2048) {
    float* row = S + (long)b * 512;
    float a = row[tid] * 0.125f, e1v = row[tid + 256] * 0.125f;
    float m = fmaxf(a, e1v);
#pragma unroll
    for (int o = 1; o < 64; o <<= 1) m = fmaxf(m, __shfl_xor(m, o));
    __shared__ float red[4];
    __shared__ float red2[4];
    int wid = tid >> 6;
    if ((tid & 63) == 0) red[wid] = m;
    __syncthreads();
    m = fmaxf(fmaxf(red[0], red[1]), fmaxf(red[2], red[3]));
    float e0 = __expf(a - m), e1 = __expf(e1v - m);
    float s = e0 + e1;
#pragma unroll
    for (int o = 1; o < 64; o <<= 1) s += __shfl_xor(s, o);
    if ((tid & 63) == 0) red2[wid] = s;
    __syncthreads();
    s = red2[0] + red2[1] + red2[2] + red2[3];
    float inv = fast_rcp(s);
    row[tid] = e0 * inv; row[tid + 256] = e1 * inv;
  } else {
    int idx = (b - 2048) * 256 + tid;
    int hh = idx >> 15;
    int r = idx & 32767;
    int d = r >> 9, n = r & 511;
    vt[idx] = (bf16)qkv[(long)n * 768 + 512 + hh * 64 + d];
  }
}

// ---------------- LayerNorm — round-5 verbatim ----------------
__global__ __launch_bounds__(256) void ln_kernel(
    const float* __restrict__ X, const float* __restrict__ sc,
    const float* __restrict__ bi, float* __restrict__ Y)
{
  int row = blockIdx.x, tid = threadIdx.x;
  float v = X[(long)row * 256 + tid];
  float s = v;
#pragma unroll
  for (int o = 1; o < 64; o <<= 1) s += __shfl_xor(s, o);
  __shared__ float r1[4];
  __shared__ float r2[4];
  if ((tid & 63) == 0) r1[tid >> 6] = s;
  __syncthreads();
  float mean = (r1[0] + r1[1] + r1[2] + r1[3]) * (1.f / 256.f);
  float d = v - mean;
  float t = d * d;
#pragma unroll
  for (int o = 1; o < 64; o <<= 1) t += __shfl_xor(t, o);
  if ((tid & 63) == 0) r2[tid >> 6] = t;
  __syncthreads();
  float var = (r2[0] + r2[1] + r2[2] + r2[3]) * (1.f / 256.f);
  Y[(long)row * 256 + tid] = d * rsqrtf(var + 1e-5f) * sc[tid] + bi[tid];
}

// ---------------- tail: aiaj (y<8) + coord-hidden (y>=8) — round-14 validated ----------------
__global__ __launch_bounds__(256) void tail_kernel(
    const float* __restrict__ hsrc,
    const bf16* __restrict__ WDP, const float* __restrict__ b512, float* __restrict__ aiaj,
    const bf16* __restrict__ Wcp, const float* __restrict__ cpb1, float* __restrict__ ct)
{
  const int y = blockIdx.y;
  const bf16* W; const float* bias; float* C; int ldc, n0; bool act;
  if (y < 8) { W = WDP; bias = b512; C = aiaj; ldc = 512; n0 = y * 64; act = false; }
  else       { W = Wcp; bias = cpb1; C = ct;   ldc = 256; n0 = (y - 8) * 64; act = true; }
  const int m0 = blockIdx.x * 64;
  __shared__ bf16 As[64][72];
  __shared__ bf16 Ws[64][72];
  const int tid = threadIdx.x;
  const int lane = tid & 63, wid = tid >> 6;
  const int wm = (wid & 1) * 32, wn = (wid >> 1) * 32;
  const int rr = lane & 15, kg = (lane >> 4) << 3;
  f32x4 acc[2][2] = {};
  float4 rA[4];
  uint2  rWh[4];
  auto load_tile = [&](int k0) {
#pragma unroll
    for (int r = 0; r < 4; ++r) {
      int lin = tid + r * 256;
      int row = lin >> 4, kc = (lin & 15) << 2;
      rA[r] = *(const float4*)&hsrc[(long)(m0 + row) * 256 + k0 + kc];
      rWh[r] = *(const uint2*)&W[(long)(n0 + row) * 256 + k0 + kc];
    }
  };
  auto store_tile = [&]() {
#pragma unroll
    for (int r = 0; r < 4; ++r) {
      int lin = tid + r * 256;
      int row = lin >> 4, kc = (lin & 15) << 2;
      As[row][kc] = (bf16)rA[r].x; As[row][kc + 1] = (bf16)rA[r].y;
      As[row][kc + 2] = (bf16)rA[r].z; As[row][kc + 3] = (bf16)rA[r].w;
      *(uint2*)&Ws[row][kc] = rWh[r];
    }
  };
  auto do_mfma = [&]() {
#pragma unroll
    for (int ks = 0; ks < 2; ++ks) {
      const int kk = ks * 32 + kg;
      bf16x8 a0 = *(const bf16x8*)&As[wm + rr][kk];
      bf16x8 a1 = *(const bf16x8*)&As[wm + 16 + rr][kk];
      bf16x8 b0 = *(const bf16x8*)&Ws[wn + rr][kk];
      bf16x8 b1 = *(const bf16x8*)&Ws[wn + 16 + rr][kk];
      acc[0][0] = MFMA16(a0, b0, acc[0][0]);
      acc[0][1] = MFMA16(a0, b1, acc[0][1]);
      acc[1][0] = MFMA16(a1, b0, acc[1][0]);
      acc[1][1] = MFMA16(a1, b1, acc[1][1]);
    }
  };
  load_tile(0);
  store_tile();
  __syncthreads();
  for (int k0 = 64; k0 < 256; k0 += 64) {
    load_tile(k0);
    do_mfma();
    __syncthreads();
    store_tile();
    __syncthreads();
  }
  do_mfma();
  const int rg = lane >> 4;
#pragma unroll
  for (int mi = 0; mi < 2; ++mi)
#pragma unroll
    for (int ni = 0; ni < 2; ++ni)
#pragma unroll
      for (int r = 0; r < 4; ++r) {
        int gm = m0 + wm + mi * 16 + rg * 4 + r;
        int gn = n0 + wn + ni * 16 + rr;
        float v = acc[mi][ni][r] + bias[gn];
        if (act) v = silu_f(v);
        C[(long)gm * ldc + gn] = v;
      }
}

// ---------------- pair2 v4 — round-10 validated (87 µs) ----------------
#define P2_BUILD(CIDX, TBUF)                                                     \
  {                                                                              \
    const int j0b = jbase + (CIDX) * 32;                                         \
    const float* ajp = aj + (long)(j0b + pp) * 512;                              \
    _Pragma("unroll")                                                            \
    for (int r = 0; r < 4; ++r) {                                                \
      int kk = kb + 8 * r;                                                       \
      float4 a0 = *(const float4*)(ajp + kk * 8);                                \
      float4 a1 = *(const float4*)(ajp + kk * 8 + 4);                            \
      const float* aip = ai_s + kk * 8;                                          \
      bf16x8 tv;                                                                 \
      tv[0] = (bf16)silu_f(a0.x + aip[0]); tv[1] = (bf16)silu_f(a0.y + aip[1]);  \
      tv[2] = (bf16)silu_f(a0.z + aip[2]); tv[3] = (bf16)silu_f(a0.w + aip[3]);  \
      tv[4] = (bf16)silu_f(a1.x + aip[4]); tv[5] = (bf16)silu_f(a1.y + aip[5]);  \
      tv[6] = (bf16)silu_f(a1.z + aip[6]); tv[7] = (bf16)silu_f(a1.w + aip[7]);  \
      *(bf16x8*)&TBUF[(kk * 32 + pp) * 8] = tv;                                  \
    }                                                                            \
  }

#define P2_MFMA(TBUF, ACC)                                                       \
  _Pragma("unroll")                                                              \
  for (int ks = 0; ks < 8; ++ks) {                                               \
    bf16x8 af0 = *(const bf16x8*)&TBUF[((ks * 4 + kq) * 32 + l15) * 8];          \
    bf16x8 af1 = *(const bf16x8*)&TBUF[((ks * 4 + kq) * 32 + 16 + l15) * 8];     \
    _Pragma("unroll")                                                            \
    for (int nt = 0; nt < 4; ++nt) {                                             \
      bf16x8 bfv = *(const bf16x8*)(w2base + (long)(nt * 8 + ks) * 512);         \
      ACC[0][nt] = MFMA16(af0, bfv, ACC[0][nt]);                                 \
      ACC[1][nt] = MFMA16(af1, bfv, ACC[1][nt]);                                 \
    }                                                                            \
  }

#define P2_EPI(ACC, PBUF)                                                        \
  _Pragma("unroll")                                                              \
  for (int Mt = 0; Mt < 2; ++Mt)                                                 \
    _Pragma("unroll")                                                            \
    for (int r = 0; r < 4; ++r) {                                                \
      float s = silu_f(ACC[Mt][0][r] + b2v[0]) * w3v[0]                          \
              + silu_f(ACC[Mt][1][r] + b2v[1]) * w3v[1]                          \
              + silu_f(ACC[Mt][2][r] + b2v[2]) * w3v[2]                          \
              + silu_f(ACC[Mt][3][r] + b2v[3]) * w3v[3];                         \
      s += __shfl_xor(s, 1); s += __shfl_xor(s, 2);                              \
      s += __shfl_xor(s, 4); s += __shfl_xor(s, 8);                              \
      if (l15 == 0) PBUF[Mt * 16 + kq * 4 + r][w] = s;                           \
    }

#define P2_DIST(CIDX, PBUF)                                                      \
  if (tid < 32) {                                                                \
    float s = PBUF[tid][0] + PBUF[tid][1] + PBUF[tid][2] + PBUF[tid][3] + b3v;   \
    float dd = fmaxf(s, 0.f) + log1pf(__expf(-fabsf(s)));                        \
    dout[(long)i * 512 + jbase + (CIDX) * 32 + tid] = dd;                        \
  }

__global__ __launch_bounds__(256, 2) void pair2_kernel(
    const float* __restrict__ ai, const float* __restrict__ aj,
    const bf16* __restrict__ W2P, const float* __restrict__ b2g,
    const float* __restrict__ w3g, const float* __restrict__ b3p,
    float* __restrict__ dout)
{
  __shared__ float ai_s[256];
  __shared__ bf16 t0_s[32 * 256];
  __shared__ bf16 t1_s[32 * 256];
  __shared__ float p0_s[32][4];
  __shared__ float p1_s[32][4];
  const int tid = threadIdx.x, lane = tid & 63, w = tid >> 6;
  const int l15 = lane & 15, kq = lane >> 4;
  const int pp = tid & 31, kb = tid >> 5;
  const int i = blockIdx.x >> 1, half = blockIdx.x & 1;
  const int jbase = half * 256;
  const float b3v = b3p[0];

  ai_s[tid] = ai[(long)i * 512 + tid];

  float b2v[4], w3v[4];
#pragma unroll
  for (int nt = 0; nt < 4; ++nt) {
    int ntg = w * 4 + nt;
    b2v[nt] = b2g[ntg * 16 + l15];
    w3v[nt] = w3g[ntg * 16 + l15];
  }
  const bf16* w2base = W2P + ((long)((w * 128 + kq) * 16 + l15)) * 8;
  __syncthreads();

  P2_BUILD(0, t0_s);
  __syncthreads();
#pragma unroll 1
  for (int cp = 0; cp < 4; ++cp) {
    const int c0 = cp * 2, c1 = cp * 2 + 1;
    {
      f32x4 acc[2][4] = {};
      P2_MFMA(t0_s, acc);
      P2_BUILD(c1, t1_s);
      P2_EPI(acc, p0_s);
    }
    __syncthreads();
    P2_DIST(c0, p0_s);
    {
      f32x4 acc[2][4] = {};
      P2_MFMA(t1_s, acc);
      if (cp < 3) P2_BUILD(c1 + 1, t0_s);
      P2_EPI(acc, p1_s);
    }
    __syncthreads();
    P2_DIST(c1, p1_s);
  }
}

// ---------------- symmetrize (b<1024) + coord final (b>=1024) — round-14 validated ----------------
__global__ __launch_bounds__(256) void symcoord_kernel(
    float* __restrict__ dist,
    const float* __restrict__ ct, const float* __restrict__ w2,
    const float* __restrict__ b2, float* __restrict__ out)
{
  const int b = blockIdx.x, tid = threadIdx.x;
  if (b < 1024) {
    int idx = b * 256 + tid;
    int i = idx >> 9, j = idx & 511;
    if (i < j) {
      float a = dist[idx];
      float bb = dist[(long)j * 512 + i];
      float m = 0.5f * (a + bb);
      dist[idx] = m;
      dist[(long)j * 512 + i] = m;
    }
  } else {
    int t = (b - 1024) * 256 + tid;
    if (t >= 1536) return;
    int row = t / 3, c = t - row * 3;
    float s = b2[c];
    const float* a = &ct[(long)row * 256];
    const float* wp = &w2[c * 256];
    for (int k = 0; k < 256; ++k) s += a[k] * wp[k];
    out[t] = s;
  }
}

extern "C" void kernel_launch(void* const* d_in, const int* in_sizes, int n_in,
                              void* d_out, int out_size, void* d_ws, size_t ws_size,
                              hipStream_t stream) {
  const float* z        = (const float*)d_in[0];
  const float* z_global = (const float*)d_in[1];
  const int*   atom_t   = (const int*)d_in[2];
  const float* emb      = (const float*)d_in[3];
  const float* ip_w1 = (const float*)d_in[4];  const float* ip_b1 = (const float*)d_in[5];
  const float* ip_w2 = (const float*)d_in[6];  const float* ip_b2 = (const float*)d_in[7];
  const float* gp_w1 = (const float*)d_in[8];  const float* gp_b1 = (const float*)d_in[9];
  const float* gp_w2 = (const float*)d_in[10]; const float* gp_b2 = (const float*)d_in[11];
  const float* wqkv  = (const float*)d_in[12]; const float* bqkv  = (const float*)d_in[13];
  const float* wo    = (const float*)d_in[14]; const float* bo    = (const float*)d_in[15];
  const float* ln1s  = (const float*)d_in[16]; const float* ln1b  = (const float*)d_in[17];
  const float* w1    = (const float*)d_in[18]; const float* b1    = (const float*)d_in[19];
  const float* w2    = (const float*)d_in[20]; const float* b2    = (const float*)d_in[21];
  const float* ln2s  = (const float*)d_in[22]; const float* ln2b  = (const float*)d_in[23];
  const float* dpw1  = (const float*)d_in[24]; const float* dpb1  = (const float*)d_in[25];
  const float* dpw2  = (const float*)d_in[26]; const float* dpb2  = (const float*)d_in[27];
  const float* dpw3  = (const float*)d_in[28]; const float* dpb3  = (const float*)d_in[29];
  const float* cpw1  = (const float*)d_in[30]; const float* cpb1  = (const float*)d_in[31];
  const float* cpw2  = (const float*)d_in[32]; const float* cpb2  = (const float*)d_in[33];

  char* ws = (char*)d_ws;
  bf16*  WB   = (bf16*)ws;
  float* zin  = (float*)(ws + F_ZIN);
  float* g    = (float*)(ws + F_G);
  float* h    = (float*)(ws + F_H);
  float* qkv  = (float*)(ws + F_QKV);
  float* S    = (float*)(ws + F_S);
  bf16*  Vt   = (bf16*)(ws + F_VT);
  float* o    = (float*)(ws + F_O);
  float* t1   = (float*)(ws + F_T1);
  bf16*  W2P  = (bf16*)(ws + O_W2P);
  bf16*  WDP  = (bf16*)(ws + O_WDP);
  float* b512 = (float*)(ws + O_B512);
  float* ff1  = S;
  float* aiaj = S;
  float* out  = (float*)d_out;
  float* xout = out;
  float* dist = out + 1536;

  prep_kernel<<<3218, 256, 0, stream>>>(ip_w1, ip_w2, wqkv, wo, w1, w2, dpw1, dpw2, cpw1, WB,
      z, atom_t, emb, z_global, gp_w1, gp_b1, gp_w2, gp_b2, dpb1,
      zin, W2P, WDP, g, b512);

  gemm_kernel<1, bf16><<<dim3(8, 4, 1), 256, 0, stream>>>(zin, 192, 0, WB + WB_IPW1, 192, 0,
      ip_b1, nullptr, 0, 0, t1, 256, 0, 192);
  gemm_kernel<0, bf16><<<dim3(8, 4, 1), 256, 0, stream>>>(t1, 256, 0, WB + WB_IPW2, 256, 0,
      ip_b2, g, 0, 0, h, 256, 0, 256);

  for (int l = 0; l < 3; ++l) {
    const bf16* wq = WB + WB_QKV + (long)l * 768 * 256;
    gemm_kernel<0, bf16><<<dim3(8, 12, 1), 256, 0, stream>>>(h, 256, 0, wq, 256, 0,
        bqkv + l * 768, nullptr, 0, 0, qkv, 768, 0, 256);
    gemm_kernel<0, float><<<dim3(8, 8, 4), 256, 0, stream>>>(qkv, 768, 64, qkv + 256, 768, 64,
        nullptr, nullptr, 0, 0, S, 512, 262144, 64);
    softvt_kernel<<<2560, 256, 0, stream>>>(S, qkv, Vt);
    gemm_kernel<0, bf16><<<dim3(8, 1, 4), 256, 0, stream>>>(S, 512, 262144, Vt, 512, 32768,
        nullptr, nullptr, 0, 0, o, 256, 64, 512);
    gemm_kernel<0, bf16><<<dim3(8, 4, 1), 256, 0, stream>>>(o, 256, 0,
        WB + WB_WO + (long)l * 65536, 256, 0, bo + l * 256, h, 256, 0, t1, 256, 0, 256);
    ln_kernel<<<512, 256, 0, stream>>>(t1, ln1s + l * 256, ln1b + l * 256, h);
    gemm_kernel<2, bf16><<<dim3(8, 16, 1), 256, 0, stream>>>(h, 256, 0,
        WB + WB_W1 + (long)l * 262144, 256, 0, b1 + l * 1024, nullptr, 0, 0, ff1, 1024, 0, 256);
    gemm_kernel<0, bf16><<<dim3(8, 4, 1), 256, 0, stream>>>(ff1, 1024, 0,
        WB + WB_W2 + (long)l * 262144, 1024, 0, b2 + l * 256, h, 256, 0, t1, 256, 0, 1024);
    ln_kernel<<<512, 256, 0, stream>>>(t1, ln2s + l * 256, ln2b + l * 256, h);
  }

  // aiaj (y<8) + coord hidden (y>=8), both from h
  tail_kernel<<<dim3(8, 12), 256, 0, stream>>>(h, WDP, b512, aiaj,
      WB + WB_CPW1, cpb1, t1);
  pair2_kernel<<<1024, 256, 0, stream>>>(aiaj, aiaj + 256, W2P, dpb2, dpw3, dpb3, dist);
  symcoord_kernel<<<1030, 256, 0, stream>>>(dist, t1, cpw2, cpb2, xout);
}